// Round 9
// baseline (273.605 us; speedup 1.0000x reference)
//
#include <hip/hip_runtime.h>
#include <hip/hip_bf16.h>

#define DIM 128
typedef __hip_bfloat16 bf16;
typedef __attribute__((ext_vector_type(8))) short bf16x8;   // 8 bf16 = 4 VGPRs
typedef __attribute__((ext_vector_type(4))) float f32x4;

// ============================ K1: prep ======================================
// blocks 0..63: zero cnt; block 64: head=0 + int-width detect (first 16K edges)
// flagI: ==0 -> edge_index is int64 (odd 32-bit words of src half all zero)
__global__ void prep_kernel(int* __restrict__ cnt, int N, const int* __restrict__ ei,
                            int E, int* __restrict__ misc) {
    if (blockIdx.x < 64) {
        int stride = 64 * 256;
        for (int i = blockIdx.x * 256 + threadIdx.x; i < N; i += stride) cnt[i] = 0;
    } else {
        __shared__ int s_or;
        if (threadIdx.x == 0) { s_or = 0; misc[0] = 0; }     // head
        __syncthreads();
        int lim = E < 16384 ? E : 16384;
        int acc = 0;
        for (int j = threadIdx.x; j < lim; j += 256) acc |= ei[2 * j + 1];
        if (acc) atomicOr(&s_or, 1);
        __syncthreads();
        if (threadIdx.x == 0) misc[1] = s_or;                // flagI
    }
}

// ============================ K2: count + swizzle ===========================
// blocks 0..15: swizzle W1/W2 f32 -> bf16 B-fragment order; blocks 16+: count.
// frag f = kt*8+nt holds B[k][n], k in [kt*32,kt*32+32), n in [nt*16,nt*16+16)
// lane l supplies n = l&15, k = (l>>4)*8 + j -> Wsw[(f*64+l)*8 + j]
__global__ void count_swizzle(const int* __restrict__ ei, int E,
                              const int* __restrict__ misc, int* __restrict__ cnt,
                              const float* __restrict__ W1, const float* __restrict__ W2,
                              bf16* __restrict__ Wsw1, bf16* __restrict__ Wsw2) {
    if (blockIdx.x < 16) {
        int id = blockIdx.x * 256 + threadIdx.x;             // 0..4095
        const float* W = (id < 2048) ? W1 : W2;
        bf16* Wsw = (id < 2048) ? Wsw1 : Wsw2;
        int t = id & 2047;
        int f = t >> 6, l = t & 63;
        int kt = f >> 3, nt = f & 7;
        int q = l >> 4, m = l & 15;
        bf16 tmp[8];
        #pragma unroll
        for (int j = 0; j < 8; ++j)
            tmp[j] = __float2bfloat16(W[(size_t)(kt * 32 + q * 8 + j) * DIM + nt * 16 + m]);
        *(bf16x8*)(Wsw + (size_t)t * 8) = *(const bf16x8*)tmp;
        return;
    }
    int e = (blockIdx.x - 16) * 256 + threadIdx.x;
    if (e >= E) return;
    int d = (misc[1] == 0) ? ei[2 * E + 2 * e] : ei[E + e];
    atomicAdd(&cnt[d], 1);
}

// ============================ K3: slab alloc ================================
__global__ void alloc_kernel(const int* __restrict__ cnt, int* __restrict__ rowstart,
                             int* __restrict__ cursor, float* __restrict__ dis,
                             int* __restrict__ head, int N) {
    int i = blockIdx.x * blockDim.x + threadIdx.x;
    if (i >= N) return;
    int c = cnt[i];
    int s = atomicAdd(head, c);
    rowstart[i] = s;
    cursor[i] = s;
    dis[i] = rsqrtf((float)(c + 1));   // +1 self loop
}

// ============================ K4: fill + gemm1 ==============================
// Y[node][c] = bf16((X[node,:]@W[:,c]) * dis[node]); wave = 16 nodes x 128 cols
template <bool XF32>
__device__ __forceinline__ void gemm_body(const void* __restrict__ Xv,
                                          const bf16* __restrict__ Wsw,
                                          const float* __restrict__ dis,
                                          bf16* __restrict__ Y, int N,
                                          int gw, int nw, int lane) {
    int m = lane & 15, q = lane >> 4;
    const bf16x8* bp = (const bf16x8*)Wsw;          // frag f at bp[f*64 + lane]
    for (int t = gw; t * 16 + 16 <= N; t += nw) {
        int base = t * 16;
        bf16x8 a[4];
        if (XF32) {
            const float* xp = (const float*)Xv + (size_t)(base + m) * DIM + q * 8;
            #pragma unroll
            for (int kt = 0; kt < 4; ++kt) {
                float4 v0 = *(const float4*)(xp + kt * 32);
                float4 v1 = *(const float4*)(xp + kt * 32 + 4);
                bf16 tt[8] = {__float2bfloat16(v0.x), __float2bfloat16(v0.y),
                              __float2bfloat16(v0.z), __float2bfloat16(v0.w),
                              __float2bfloat16(v1.x), __float2bfloat16(v1.y),
                              __float2bfloat16(v1.z), __float2bfloat16(v1.w)};
                a[kt] = *(const bf16x8*)tt;
            }
        } else {
            const bf16* xp = (const bf16*)Xv + (size_t)(base + m) * DIM + q * 8;
            #pragma unroll
            for (int kt = 0; kt < 4; ++kt)
                a[kt] = *(const bf16x8*)(xp + kt * 32);
        }
        f32x4 acc[8];
        #pragma unroll
        for (int nt = 0; nt < 8; ++nt) acc[nt] = (f32x4){0.f, 0.f, 0.f, 0.f};
        #pragma unroll
        for (int kt = 0; kt < 4; ++kt) {
            #pragma unroll
            for (int nt = 0; nt < 8; ++nt) {
                bf16x8 b = bp[(size_t)(kt * 8 + nt) * 64 + lane];
                acc[nt] = __builtin_amdgcn_mfma_f32_16x16x32_bf16(a[kt], b, acc[nt], 0, 0, 0);
            }
        }
        // D: row (node) = q*4 + r, col (channel) = nt*16 + m  [m89/m91-verified]
        float dr[4];
        #pragma unroll
        for (int r = 0; r < 4; ++r) dr[r] = dis[base + q * 4 + r];
        #pragma unroll
        for (int nt = 0; nt < 8; ++nt)
            #pragma unroll
            for (int r = 0; r < 4; ++r)
                Y[(size_t)(base + q * 4 + r) * DIM + nt * 16 + m] =
                    __float2bfloat16(acc[nt][r] * dr[r]);
    }
}

#define FILL_BLK 448
__global__ void fill_gemm1(const int* __restrict__ ei, int E,
                           const int* __restrict__ misc,
                           int* __restrict__ cursor, int* __restrict__ csr,
                           const float* __restrict__ x, const bf16* __restrict__ Wsw1,
                           const float* __restrict__ dis, bf16* __restrict__ Y, int N) {
    if (blockIdx.x < FILL_BLK) {
        int flagI = misc[1];
        int stride = FILL_BLK * 256;
        for (int e = blockIdx.x * 256 + threadIdx.x; e < E; e += stride) {
            int s, d;
            if (flagI == 0) { s = ei[2 * e]; d = ei[2 * E + 2 * e]; }
            else            { s = ei[e];     d = ei[E + e]; }
            int p = atomicAdd(&cursor[d], 1);
            csr[p] = s;
        }
    } else {
        int wid = threadIdx.x >> 6, lane = threadIdx.x & 63;
        int gw = (blockIdx.x - FILL_BLK) * 4 + wid;
        int nw = (gridDim.x - FILL_BLK) * 4;
        gemm_body<true>(x, Wsw1, dis, Y, N, gw, nw, lane);
    }
}

// ============================ K6: gemm2 =====================================
__global__ void gemm2(const bf16* __restrict__ H, const bf16* __restrict__ Wsw2,
                      const float* __restrict__ dis, bf16* __restrict__ Y, int N) {
    int wid = threadIdx.x >> 6, lane = threadIdx.x & 63;
    gemm_body<false>(H, Wsw2, dis, Y, N, blockIdx.x * 4 + wid, gridDim.x * 4, lane);
}

// ============================ K5/K7: aggregate ==============================
// out[n][c] = relu(dis[n]*(y[n][c]+sum y[src][c])+b[c])
// Half-wave (32 lanes) per node; lane covers 4 channels via one uint2 (2x bf16x2).
// 8-deep edge unroll -> 16 row-gathers in flight per wave (2 nodes x 8).
__device__ __forceinline__ void bfacc2(float* a, uint2 v) {
    a[0] += __uint_as_float(v.x << 16);
    a[1] += __uint_as_float(v.x & 0xffff0000u);
    a[2] += __uint_as_float(v.y << 16);
    a[3] += __uint_as_float(v.y & 0xffff0000u);
}

template <bool FINAL>
__global__ __launch_bounds__(256, 8)
void aggregate_bf(const uint2* __restrict__ Y, const int* __restrict__ rowstart,
                  const int* __restrict__ cnt, const int* __restrict__ csr,
                  const float* __restrict__ dis, const float* __restrict__ bias,
                  uint2* __restrict__ Hb, float4* __restrict__ Of, int N) {
    int wave = threadIdx.x >> 6;
    int lane = threadIdx.x & 63;
    int sub = lane >> 5, cl = lane & 31;        // half-wave id, uint2 index in row
    int node = blockIdx.x * 8 + wave * 2 + sub;
    if (node >= N) return;
    int e0 = rowstart[node], e1 = e0 + cnt[node];

    float acc[8][4];
    #pragma unroll
    for (int j = 0; j < 8; ++j)
        #pragma unroll
        for (int k = 0; k < 4; ++k) acc[j][k] = 0.f;
    bfacc2(acc[7], Y[(size_t)node * 32 + cl]);          // self loop

    int e = e0;
    while (e + 8 <= e1) {
        int s[8];
        #pragma unroll
        for (int j = 0; j < 8; ++j) s[j] = csr[e + j];
        uint2 v[8];
        #pragma unroll
        for (int j = 0; j < 8; ++j) v[j] = Y[(size_t)s[j] * 32 + cl];
        #pragma unroll
        for (int j = 0; j < 8; ++j) bfacc2(acc[j], v[j]);
        e += 8;
    }
    if (e + 4 <= e1) {
        int s[4];
        #pragma unroll
        for (int j = 0; j < 4; ++j) s[j] = csr[e + j];
        uint2 v[4];
        #pragma unroll
        for (int j = 0; j < 4; ++j) v[j] = Y[(size_t)s[j] * 32 + cl];
        #pragma unroll
        for (int j = 0; j < 4; ++j) bfacc2(acc[j], v[j]);
        e += 4;
    }
    for (; e < e1; ++e)
        bfacc2(acc[0], Y[(size_t)csr[e] * 32 + cl]);

    float s0 = ((acc[0][0] + acc[1][0]) + (acc[2][0] + acc[3][0])) +
               ((acc[4][0] + acc[5][0]) + (acc[6][0] + acc[7][0]));
    float s1 = ((acc[0][1] + acc[1][1]) + (acc[2][1] + acc[3][1])) +
               ((acc[4][1] + acc[5][1]) + (acc[6][1] + acc[7][1]));
    float s2 = ((acc[0][2] + acc[1][2]) + (acc[2][2] + acc[3][2])) +
               ((acc[4][2] + acc[5][2]) + (acc[6][2] + acc[7][2]));
    float s3 = ((acc[0][3] + acc[1][3]) + (acc[2][3] + acc[3][3])) +
               ((acc[4][3] + acc[5][3]) + (acc[6][3] + acc[7][3]));
    float4 b = ((const float4*)bias)[cl];
    float ds = dis[node];
    float v0 = fmaxf(ds * s0 + b.x, 0.f);
    float v1 = fmaxf(ds * s1 + b.y, 0.f);
    float v2 = fmaxf(ds * s2 + b.z, 0.f);
    float v3 = fmaxf(ds * s3 + b.w, 0.f);
    if (FINAL) {
        Of[(size_t)node * 32 + cl] = make_float4(v0, v1, v2, v3);
    } else {
        bf16 t[4] = {__float2bfloat16(v0), __float2bfloat16(v1),
                     __float2bfloat16(v2), __float2bfloat16(v3)};
        Hb[(size_t)node * 32 + cl] = *(const uint2*)t;
    }
}

// ============================ launcher ======================================
extern "C" void kernel_launch(void* const* d_in, const int* in_sizes, int n_in,
                              void* d_out, int out_size, void* d_ws, size_t ws_size,
                              hipStream_t stream) {
    const float* x  = (const float*)d_in[0];
    const int*   ei = (const int*)d_in[1];
    const float* W1 = (const float*)d_in[2];
    const float* b1 = (const float*)d_in[3];
    const float* W2 = (const float*)d_in[4];
    const float* b2 = (const float*)d_in[5];

    int N = in_sizes[0] / DIM;      // 50000
    int E = in_sizes[1] / 2;        // 600000

    char* w = (char*)d_ws;
    size_t used = 0;
    auto carve = [&](size_t bytes) {
        char* p = w + used;
        used += (bytes + 255) & ~(size_t)255;
        return p;
    };
    int*   misc     = (int*)  carve(256);               // [0]=head [1]=flagI
    int*   cnt      = (int*)  carve((size_t)N * 4);
    int*   rowstart = (int*)  carve((size_t)N * 4);
    int*   cursor   = (int*)  carve((size_t)N * 4);
    int*   csr      = (int*)  carve((size_t)E * 4);
    float* dis      = (float*)carve((size_t)N * 4);
    bf16*  ybuf     = (bf16*) carve((size_t)N * DIM * 2);
    bf16*  hbuf     = (bf16*) carve((size_t)N * DIM * 2);
    bf16*  Wsw1     = (bf16*) carve((size_t)DIM * DIM * 2);
    bf16*  Wsw2     = (bf16*) carve((size_t)DIM * DIM * 2);

    int* head = misc + 0;

    prep_kernel<<<65, 256, 0, stream>>>(cnt, N, ei, E, misc);
    count_swizzle<<<16 + (E + 255) / 256, 256, 0, stream>>>(ei, E, misc, cnt,
                                                            W1, W2, Wsw1, Wsw2);
    alloc_kernel<<<(N + 255) / 256, 256, 0, stream>>>(cnt, rowstart, cursor, dis, head, N);

    // K4: fill (448 blocks) || gemm1 (784 blocks -> 3136 waves for 3125 tiles)
    fill_gemm1<<<FILL_BLK + 784, 256, 0, stream>>>(ei, E, misc, cursor, csr,
                                                   x, Wsw1, dis, ybuf, N);

    int ablocks = (N + 7) / 8;              // 6250
    aggregate_bf<false><<<ablocks, 256, 0, stream>>>((const uint2*)ybuf, rowstart, cnt,
                                                     csr, dis, b1, (uint2*)hbuf, nullptr, N);
    gemm2<<<784, 256, 0, stream>>>(hbuf, Wsw2, dis, ybuf, N);
    aggregate_bf<true><<<ablocks, 256, 0, stream>>>((const uint2*)ybuf, rowstart, cnt,
                                                    csr, dis, b2, nullptr, (float4*)d_out, N);
}

// Round 10
// 233.709 us; speedup vs baseline: 1.1707x; 1.1707x over previous
//
#include <hip/hip_runtime.h>
#include <hip/hip_bf16.h>

#define DIM 128
#define CHUNK 8192
typedef __hip_bfloat16 bf16;
typedef __attribute__((ext_vector_type(8))) short bf16x8;   // 8 bf16 = 4 VGPRs
typedef __attribute__((ext_vector_type(4))) float f32x4;

// ============================ K1: prep ======================================
// b0: zero bucket counts; b1: int-width detect (flagI: 0 -> int64); b2..17: W swizzle
__global__ void prep_kernel(int* __restrict__ bcnt, int nbuck,
                            const int* __restrict__ ei, int E, int* __restrict__ misc,
                            const float* __restrict__ W1, const float* __restrict__ W2,
                            bf16* __restrict__ Wsw1, bf16* __restrict__ Wsw2) {
    if (blockIdx.x == 0) {
        for (int i = threadIdx.x; i <= nbuck; i += 256) bcnt[i] = 0;
    } else if (blockIdx.x == 1) {
        __shared__ int s_or;
        if (threadIdx.x == 0) s_or = 0;
        __syncthreads();
        int lim = E < 16384 ? E : 16384;
        int acc = 0;
        for (int j = threadIdx.x; j < lim; j += 256) acc |= ei[2 * j + 1];
        if (acc) atomicOr(&s_or, 1);
        __syncthreads();
        if (threadIdx.x == 0) misc[1] = s_or;
    } else {
        // W f32 -> bf16 B-fragment order: frag f=kt*8+nt, lane l: n=l&15, k=(l>>4)*8+j
        int id = (blockIdx.x - 2) * 256 + threadIdx.x;       // 0..4095
        const float* W = (id < 2048) ? W1 : W2;
        bf16* Wsw = (id < 2048) ? Wsw1 : Wsw2;
        int t = id & 2047;
        int f = t >> 6, l = t & 63;
        int kt = f >> 3, nt = f & 7;
        int q = l >> 4, m = l & 15;
        bf16 tmp[8];
        #pragma unroll
        for (int j = 0; j < 8; ++j)
            tmp[j] = __float2bfloat16(W[(size_t)(kt * 32 + q * 8 + j) * DIM + nt * 16 + m]);
        *(bf16x8*)(Wsw + (size_t)t * 8) = *(const bf16x8*)tmp;
    }
}

// ============================ K2: bucket count ==============================
__global__ void bucket_count(const int* __restrict__ ei, int E,
                             const int* __restrict__ misc,
                             int* __restrict__ bcnt, int nbuck) {
    __shared__ int s_cnt[512];
    for (int i = threadIdx.x; i < nbuck; i += 512) s_cnt[i] = 0;
    __syncthreads();
    int flagI = misc[1];
    int c0 = blockIdx.x * CHUNK;
    int cn = min(E - c0, CHUNK);
    for (int i = threadIdx.x; i < cn; i += 512) {
        int e = c0 + i;
        int d = (flagI == 0) ? ei[2 * E + 2 * e] : ei[E + e];
        atomicAdd(&s_cnt[d >> 7], 1);
    }
    __syncthreads();
    for (int i = threadIdx.x; i < nbuck; i += 512)
        if (s_cnt[i]) atomicAdd(&bcnt[i], s_cnt[i]);
}

// ============================ K3: bucket scan ===============================
__global__ void bucket_scan(const int* __restrict__ bcnt, int* __restrict__ bstart,
                            int* __restrict__ bcursor, int nbuck, int E) {
    __shared__ int s[512];
    int tid = threadIdx.x;
    int v = (tid < nbuck) ? bcnt[tid] : 0;
    s[tid] = v;
    __syncthreads();
    for (int off = 1; off < 512; off <<= 1) {
        int t = (tid >= off) ? s[tid - off] : 0;
        __syncthreads();
        s[tid] += t;
        __syncthreads();
    }
    if (tid < nbuck) {
        int ex = s[tid] - v;
        bstart[tid] = ex;
        bcursor[tid] = ex;
    }
    if (tid == 0) bstart[nbuck] = E;
}

// ============================ K4: bucket scatter ============================
// writes packed (src<<7 | dst&127) into per-(block,bucket) contiguous runs
__global__ void bucket_scatter(const int* __restrict__ ei, int E,
                               const int* __restrict__ misc,
                               int* __restrict__ bcursor,
                               unsigned* __restrict__ staged, int nbuck) {
    __shared__ int s_cnt[512], s_base[512], s_fill[512];
    for (int i = threadIdx.x; i < nbuck; i += 512) { s_cnt[i] = 0; s_fill[i] = 0; }
    __syncthreads();
    int flagI = misc[1];
    int c0 = blockIdx.x * CHUNK;
    int cn = min(E - c0, CHUNK);
    for (int i = threadIdx.x; i < cn; i += 512) {
        int e = c0 + i;
        int d = (flagI == 0) ? ei[2 * E + 2 * e] : ei[E + e];
        atomicAdd(&s_cnt[d >> 7], 1);
    }
    __syncthreads();
    for (int i = threadIdx.x; i < nbuck; i += 512) {
        int c = s_cnt[i];
        s_base[i] = c ? atomicAdd(&bcursor[i], c) : 0;
    }
    __syncthreads();
    for (int i = threadIdx.x; i < cn; i += 512) {
        int e = c0 + i;
        int s, d;
        if (flagI == 0) { s = ei[2 * e]; d = ei[2 * E + 2 * e]; }
        else            { s = ei[e];     d = ei[E + e]; }
        int b = d >> 7;
        int r = atomicAdd(&s_fill[b], 1);
        staged[s_base[b] + r] = ((unsigned)s << 7) | (unsigned)(d & 127);
    }
}

// ============================ K5: within-bucket sort ========================
// block per bucket: LDS counting sort by local node; emits csr/rowstart/cnt/dis
__global__ void bucket_sort(const unsigned* __restrict__ staged,
                            const int* __restrict__ bstart,
                            int* __restrict__ csr, int* __restrict__ rowstart,
                            int* __restrict__ cnt, float* __restrict__ dis, int N) {
    __shared__ int s_cnt[128], s_off[128], s_fill[128], s_scan[128];
    int b = blockIdx.x, tid = threadIdx.x;
    int seg0 = bstart[b], seg1 = bstart[b + 1];
    int n = seg1 - seg0;
    if (tid < 128) { s_cnt[tid] = 0; s_fill[tid] = 0; }
    __syncthreads();
    for (int i = tid; i < n; i += 256)
        atomicAdd(&s_cnt[staged[seg0 + i] & 127u], 1);
    __syncthreads();
    int v = (tid < 128) ? s_cnt[tid] : 0;
    if (tid < 128) s_scan[tid] = v;
    __syncthreads();
    for (int off = 1; off < 128; off <<= 1) {
        int t = (tid < 128 && tid >= off) ? s_scan[tid - off] : 0;
        __syncthreads();
        if (tid < 128) s_scan[tid] += t;
        __syncthreads();
    }
    if (tid < 128) {
        s_off[tid] = s_scan[tid] - v;
        int node = b * 128 + tid;
        if (node < N) {
            cnt[node] = v;
            rowstart[node] = seg0 + s_off[tid];
            dis[node] = rsqrtf((float)(v + 1));   // +1 self loop
        }
    }
    __syncthreads();
    for (int i = tid; i < n; i += 256) {
        unsigned p = staged[seg0 + i];
        int dl = p & 127u;
        int r = atomicAdd(&s_fill[dl], 1);
        csr[seg0 + s_off[dl] + r] = (int)(p >> 7);
    }
}

// ============================ MFMA gemm =====================================
// Y[node][c] = bf16((X[node,:]@W[:,c]) * dis[node]); wave = 16 nodes x 128 cols
template <bool XF32>
__device__ __forceinline__ void gemm_body(const void* __restrict__ Xv,
                                          const bf16* __restrict__ Wsw,
                                          const float* __restrict__ dis,
                                          bf16* __restrict__ Y, int N,
                                          int gw, int nw, int lane) {
    int m = lane & 15, q = lane >> 4;
    const bf16x8* bp = (const bf16x8*)Wsw;          // frag f at bp[f*64 + lane]
    for (int t = gw; t * 16 + 16 <= N; t += nw) {
        int base = t * 16;
        bf16x8 a[4];
        if (XF32) {
            const float* xp = (const float*)Xv + (size_t)(base + m) * DIM + q * 8;
            #pragma unroll
            for (int kt = 0; kt < 4; ++kt) {
                float4 v0 = *(const float4*)(xp + kt * 32);
                float4 v1 = *(const float4*)(xp + kt * 32 + 4);
                bf16 tt[8] = {__float2bfloat16(v0.x), __float2bfloat16(v0.y),
                              __float2bfloat16(v0.z), __float2bfloat16(v0.w),
                              __float2bfloat16(v1.x), __float2bfloat16(v1.y),
                              __float2bfloat16(v1.z), __float2bfloat16(v1.w)};
                a[kt] = *(const bf16x8*)tt;
            }
        } else {
            const bf16* xp = (const bf16*)Xv + (size_t)(base + m) * DIM + q * 8;
            #pragma unroll
            for (int kt = 0; kt < 4; ++kt)
                a[kt] = *(const bf16x8*)(xp + kt * 32);
        }
        f32x4 acc[8];
        #pragma unroll
        for (int nt = 0; nt < 8; ++nt) acc[nt] = (f32x4){0.f, 0.f, 0.f, 0.f};
        #pragma unroll
        for (int kt = 0; kt < 4; ++kt) {
            #pragma unroll
            for (int nt = 0; nt < 8; ++nt) {
                bf16x8 bfr = bp[(size_t)(kt * 8 + nt) * 64 + lane];
                acc[nt] = __builtin_amdgcn_mfma_f32_16x16x32_bf16(a[kt], bfr, acc[nt], 0, 0, 0);
            }
        }
        // D: row (node) = q*4 + r, col (channel) = nt*16 + m  [m89/m91-verified]
        float dr[4];
        #pragma unroll
        for (int r = 0; r < 4; ++r) dr[r] = dis[base + q * 4 + r];
        #pragma unroll
        for (int nt = 0; nt < 8; ++nt)
            #pragma unroll
            for (int r = 0; r < 4; ++r)
                Y[(size_t)(base + q * 4 + r) * DIM + nt * 16 + m] =
                    __float2bfloat16(acc[nt][r] * dr[r]);
    }
}

__global__ void gemm1(const float* __restrict__ X, const bf16* __restrict__ Wsw,
                      const float* __restrict__ dis, bf16* __restrict__ Y, int N) {
    int wid = threadIdx.x >> 6, lane = threadIdx.x & 63;
    gemm_body<true>(X, Wsw, dis, Y, N, blockIdx.x * 4 + wid, gridDim.x * 4, lane);
}

__global__ void gemm2(const bf16* __restrict__ H, const bf16* __restrict__ Wsw,
                      const float* __restrict__ dis, bf16* __restrict__ Y, int N) {
    int wid = threadIdx.x >> 6, lane = threadIdx.x & 63;
    gemm_body<false>(H, Wsw, dis, Y, N, blockIdx.x * 4 + wid, gridDim.x * 4, lane);
}

// ============================ aggregate =====================================
// out[n][c] = relu(dis[n]*(y[n][c]+sum y[src][c])+b[c])
// Half-wave (32 lanes) per node; lane covers 4 channels via one uint2.
__device__ __forceinline__ void bfacc2(float* a, uint2 v) {
    a[0] += __uint_as_float(v.x << 16);
    a[1] += __uint_as_float(v.x & 0xffff0000u);
    a[2] += __uint_as_float(v.y << 16);
    a[3] += __uint_as_float(v.y & 0xffff0000u);
}

template <bool FINAL>
__global__ __launch_bounds__(256, 8)
void aggregate_bf(const uint2* __restrict__ Y, const int* __restrict__ rowstart,
                  const int* __restrict__ cnt, const int* __restrict__ csr,
                  const float* __restrict__ dis, const float* __restrict__ bias,
                  uint2* __restrict__ Hb, float4* __restrict__ Of, int N) {
    int wave = threadIdx.x >> 6;
    int lane = threadIdx.x & 63;
    int sub = lane >> 5, cl = lane & 31;
    int node = blockIdx.x * 8 + wave * 2 + sub;
    if (node >= N) return;
    int e0 = rowstart[node], e1 = e0 + cnt[node];

    float acc[8][4];
    #pragma unroll
    for (int j = 0; j < 8; ++j)
        #pragma unroll
        for (int k = 0; k < 4; ++k) acc[j][k] = 0.f;
    bfacc2(acc[7], Y[(size_t)node * 32 + cl]);          // self loop

    int e = e0;
    while (e + 8 <= e1) {
        int s[8];
        #pragma unroll
        for (int j = 0; j < 8; ++j) s[j] = csr[e + j];
        uint2 v[8];
        #pragma unroll
        for (int j = 0; j < 8; ++j) v[j] = Y[(size_t)s[j] * 32 + cl];
        #pragma unroll
        for (int j = 0; j < 8; ++j) bfacc2(acc[j], v[j]);
        e += 8;
    }
    if (e + 4 <= e1) {
        int s[4];
        #pragma unroll
        for (int j = 0; j < 4; ++j) s[j] = csr[e + j];
        uint2 v[4];
        #pragma unroll
        for (int j = 0; j < 4; ++j) v[j] = Y[(size_t)s[j] * 32 + cl];
        #pragma unroll
        for (int j = 0; j < 4; ++j) bfacc2(acc[j], v[j]);
        e += 4;
    }
    for (; e < e1; ++e)
        bfacc2(acc[0], Y[(size_t)csr[e] * 32 + cl]);

    float s0 = ((acc[0][0] + acc[1][0]) + (acc[2][0] + acc[3][0])) +
               ((acc[4][0] + acc[5][0]) + (acc[6][0] + acc[7][0]));
    float s1 = ((acc[0][1] + acc[1][1]) + (acc[2][1] + acc[3][1])) +
               ((acc[4][1] + acc[5][1]) + (acc[6][1] + acc[7][1]));
    float s2 = ((acc[0][2] + acc[1][2]) + (acc[2][2] + acc[3][2])) +
               ((acc[4][2] + acc[5][2]) + (acc[6][2] + acc[7][2]));
    float s3 = ((acc[0][3] + acc[1][3]) + (acc[2][3] + acc[3][3])) +
               ((acc[4][3] + acc[5][3]) + (acc[6][3] + acc[7][3]));
    float4 b = ((const float4*)bias)[cl];
    float ds = dis[node];
    float v0 = fmaxf(ds * s0 + b.x, 0.f);
    float v1 = fmaxf(ds * s1 + b.y, 0.f);
    float v2 = fmaxf(ds * s2 + b.z, 0.f);
    float v3 = fmaxf(ds * s3 + b.w, 0.f);
    if (FINAL) {
        Of[(size_t)node * 32 + cl] = make_float4(v0, v1, v2, v3);
    } else {
        bf16 t[4] = {__float2bfloat16(v0), __float2bfloat16(v1),
                     __float2bfloat16(v2), __float2bfloat16(v3)};
        Hb[(size_t)node * 32 + cl] = *(const uint2*)t;
    }
}

// ============================ launcher ======================================
extern "C" void kernel_launch(void* const* d_in, const int* in_sizes, int n_in,
                              void* d_out, int out_size, void* d_ws, size_t ws_size,
                              hipStream_t stream) {
    const float* x  = (const float*)d_in[0];
    const int*   ei = (const int*)d_in[1];
    const float* W1 = (const float*)d_in[2];
    const float* b1 = (const float*)d_in[3];
    const float* W2 = (const float*)d_in[4];
    const float* b2 = (const float*)d_in[5];

    int N = in_sizes[0] / DIM;      // 50000
    int E = in_sizes[1] / 2;        // 600000
    int nbuck = (N + 127) / 128;    // 391 (<= 512 assumed by the scans)
    int nchunks = (E + CHUNK - 1) / CHUNK;  // 74

    char* w = (char*)d_ws;
    size_t used = 0;
    auto carve = [&](size_t bytes) {
        char* p = w + used;
        used += (bytes + 255) & ~(size_t)255;
        return p;
    };
    int*      misc     = (int*)     carve(256);              // [1]=flagI
    int*      bcnt     = (int*)     carve((size_t)(nbuck + 1) * 4);
    int*      bstart   = (int*)     carve((size_t)(nbuck + 1) * 4);
    int*      bcursor  = (int*)     carve((size_t)nbuck * 4);
    unsigned* staged   = (unsigned*)carve((size_t)E * 4);
    int*      csr      = (int*)     carve((size_t)E * 4);
    int*      rowstart = (int*)     carve((size_t)N * 4);
    int*      cnt      = (int*)     carve((size_t)N * 4);
    float*    dis      = (float*)   carve((size_t)N * 4);
    bf16*     ybuf     = (bf16*)    carve((size_t)N * DIM * 2);
    bf16*     hbuf     = (bf16*)    carve((size_t)N * DIM * 2);
    bf16*     Wsw1     = (bf16*)    carve((size_t)DIM * DIM * 2);
    bf16*     Wsw2     = (bf16*)    carve((size_t)DIM * DIM * 2);

    prep_kernel   <<<18, 256, 0, stream>>>(bcnt, nbuck, ei, E, misc, W1, W2, Wsw1, Wsw2);
    bucket_count  <<<nchunks, 512, 0, stream>>>(ei, E, misc, bcnt, nbuck);
    bucket_scan   <<<1, 512, 0, stream>>>(bcnt, bstart, bcursor, nbuck, E);
    bucket_scatter<<<nchunks, 512, 0, stream>>>(ei, E, misc, bcursor, staged, nbuck);
    bucket_sort   <<<nbuck, 256, 0, stream>>>(staged, bstart, csr, rowstart, cnt, dis, N);

    int ablocks = (N + 7) / 8;              // 6250
    gemm1<<<784, 256, 0, stream>>>(x, Wsw1, dis, ybuf, N);
    aggregate_bf<false><<<ablocks, 256, 0, stream>>>((const uint2*)ybuf, rowstart, cnt,
                                                     csr, dis, b1, (uint2*)hbuf, nullptr, N);
    gemm2<<<784, 256, 0, stream>>>(hbuf, Wsw2, dis, ybuf, N);
    aggregate_bf<true><<<ablocks, 256, 0, stream>>>((const uint2*)ybuf, rowstart, cnt,
                                                    csr, dis, b2, nullptr, (float4*)d_out, N);
}